// Round 2
// baseline (801.000 us; speedup 1.0000x reference)
//
#include <hip/hip_runtime.h>

// EnsembleLayer fused: y[b, n*32+c] = sum_c' M[n][c][c'] * xi[b][n][c'] + bias[n][c]
// M[n] = dec_w[n] @ enc_w[n], bias[n] = dec_w[n] @ enc_b[n] + dec_b[n]  (precomputed in ws)
//
// Memory-bound target: ~400-540 MB HBM traffic -> ~65-90us floor.
// R2: 4 outputs/thread (halve LDS reads), double-buffered pipelined K-loop,
//     precomputed M in workspace.

#define F        512
#define NC       16
#define CS       32
#define NH       16
#define NBLOCKS  2048
#define RPB      64    // rows per block
#define RPI      8     // rows per iteration
#define NITER    (RPB / RPI)   // 8

// ---------------- precompute fused M + bias into workspace ----------------
__global__ void precompute_kernel(const float* __restrict__ enc_w,
                                  const float* __restrict__ enc_b,
                                  const float* __restrict__ dec_w,
                                  const float* __restrict__ dec_b,
                                  float* __restrict__ M,      // [16][32][32]
                                  float* __restrict__ bias) { // [16][32]
    const int u = blockIdx.x * 256 + threadIdx.x;   // 512 threads: (n, c)
    if (u >= NC * CS) return;
    const int n = u >> 5;

    float m[32];
    #pragma unroll
    for (int i = 0; i < 32; ++i) m[i] = 0.f;
    float b = dec_b[u];

    for (int h = 0; h < NH; ++h) {
        const float d = dec_w[u * NH + h];
        b += d * enc_b[n * NH + h];
        const float4* ew = (const float4*)(enc_w + (n * NH + h) * CS);
        #pragma unroll
        for (int k = 0; k < 8; ++k) {
            float4 e = ew[k];
            m[4*k+0] += d * e.x;  m[4*k+1] += d * e.y;
            m[4*k+2] += d * e.z;  m[4*k+3] += d * e.w;
        }
    }
    float4* Mo = (float4*)(M + u * CS);
    #pragma unroll
    for (int k = 0; k < 8; ++k)
        Mo[k] = make_float4(m[4*k], m[4*k+1], m[4*k+2], m[4*k+3]);
    bias[u] = b;
}

// ---------------- main kernel ----------------
__global__ __launch_bounds__(256, 3)
void ensemble_kernel(const float* __restrict__ x,
                     const int*   __restrict__ clusters,
                     const float* __restrict__ M,
                     const float* __restrict__ bias,
                     float*       __restrict__ out) {
    // xi stored swizzled: value xi[n][cc] at slot n*32 + ((cc + 4n) & 31).
    // Compute read of columns 4k..4k+3 of cluster n is at slot group
    // 4*((k+n)&7): across a wave (8 clusters) the 8 groups cover all 32
    // banks, 8-lane broadcast each -> conflict-free b128 reads.
    __shared__ float s_xi[2][RPI][F];   // double buffer, 32 KB
    __shared__ int   s_tgt[F];          // src col -> swizzled LDS slot

    const int t = threadIdx.x;

    // build inverse-permutation table
    for (int j = t; j < F; j += 256) {
        int col = clusters[j];
        int nn = j >> 5, cc = j & 31;
        s_tgt[col] = (nn << 5) | ((cc + (nn << 2)) & 31);
    }

    // roles: rh = which of the 2 rows per pass; (n, c0) = 4 owned outputs
    const int rh    = t >> 7;
    const int cbase = (t & 127) << 2;   // 4 source columns this thread loads
    const int n     = (t & 127) >> 3;
    const int c0    = (t & 7) << 2;

    // load my 4 fused-M rows from ws (L2-hot after first blocks)
    float m[4][32];
    #pragma unroll
    for (int j = 0; j < 4; ++j) {
        const float4* Mr = (const float4*)(M + (n * CS + c0 + j) * CS);
        #pragma unroll
        for (int k = 0; k < 8; ++k) {
            float4 e = Mr[k];
            m[j][4*k+0] = e.x;  m[j][4*k+1] = e.y;
            m[j][4*k+2] = e.z;  m[j][4*k+3] = e.w;
        }
    }
    const float4 bv = *(const float4*)(bias + n * CS + c0);

    __syncthreads();   // s_tgt ready

    const int tgt0 = s_tgt[cbase + 0];
    const int tgt1 = s_tgt[cbase + 1];
    const int tgt2 = s_tgt[cbase + 2];
    const int tgt3 = s_tgt[cbase + 3];

    const size_t row_block = (size_t)blockIdx.x * RPB;
    const int xioff = n << 5;

    // prologue: load + scatter iteration 0 into buffer 0
    float4 v[4];
    #pragma unroll
    for (int p = 0; p < 4; ++p)
        v[p] = *(const float4*)(x + (row_block + (size_t)(p * 2 + rh)) * F + cbase);
    #pragma unroll
    for (int p = 0; p < 4; ++p) {
        float* dst = s_xi[0][p * 2 + rh];
        dst[tgt0] = v[p].x;  dst[tgt1] = v[p].y;
        dst[tgt2] = v[p].z;  dst[tgt3] = v[p].w;
    }

    for (int it = 0; it < NITER; ++it) {
        const size_t r0 = row_block + (size_t)it * RPI;

        // prefetch next iteration's rows (issues before barrier; vmcnt waited
        // only at the scatter after compute -> latency hidden)
        if (it + 1 < NITER) {
            #pragma unroll
            for (int p = 0; p < 4; ++p)
                v[p] = *(const float4*)(x + (r0 + RPI + (size_t)(p * 2 + rh)) * F + cbase);
        }

        __syncthreads();   // current buffer's scatter complete; prev compute done

        const float (*buf)[F] = s_xi[it & 1];

        // 4 passes x 2 rows (rh split) = 8 rows; 4 outputs/thread/row
        #pragma unroll
        for (int p2 = 0; p2 < 4; ++p2) {
            const int r = p2 * 2 + rh;
            const float* xr = &buf[r][xioff];
            float a0 = bv.x, a1 = bv.y, a2 = bv.z, a3 = bv.w;
            #pragma unroll
            for (int k = 0; k < 8; ++k) {
                const int kk = (k + n) & 7;
                float4 xv = *(const float4*)(xr + (kk << 2));
                a0 += m[0][4*k+0] * xv.x;  a1 += m[1][4*k+0] * xv.x;
                a2 += m[2][4*k+0] * xv.x;  a3 += m[3][4*k+0] * xv.x;
                a0 += m[0][4*k+1] * xv.y;  a1 += m[1][4*k+1] * xv.y;
                a2 += m[2][4*k+1] * xv.y;  a3 += m[3][4*k+1] * xv.y;
                a0 += m[0][4*k+2] * xv.z;  a1 += m[1][4*k+2] * xv.z;
                a2 += m[2][4*k+2] * xv.z;  a3 += m[3][4*k+2] * xv.z;
                a0 += m[0][4*k+3] * xv.w;  a1 += m[1][4*k+3] * xv.w;
                a2 += m[2][4*k+3] * xv.w;  a3 += m[3][4*k+3] * xv.w;
            }
            *(float4*)(out + (r0 + (size_t)r) * F + xioff + c0) =
                make_float4(a0, a1, a2, a3);
        }

        // scatter prefetched rows into the other buffer (no extra barrier:
        // all threads already passed this iteration's barrier after finishing
        // their previous-iteration reads of that buffer)
        if (it + 1 < NITER) {
            #pragma unroll
            for (int p = 0; p < 4; ++p) {
                float* dst = s_xi[(it + 1) & 1][p * 2 + rh];
                dst[tgt0] = v[p].x;  dst[tgt1] = v[p].y;
                dst[tgt2] = v[p].z;  dst[tgt3] = v[p].w;
            }
        }
    }
}

extern "C" void kernel_launch(void* const* d_in, const int* in_sizes, int n_in,
                              void* d_out, int out_size, void* d_ws, size_t ws_size,
                              hipStream_t stream) {
    const float* x      = (const float*)d_in[0];
    const int*   clus   = (const int*)  d_in[1];
    const float* enc_w  = (const float*)d_in[2];
    const float* enc_b  = (const float*)d_in[3];
    const float* dec_w  = (const float*)d_in[4];
    const float* dec_b  = (const float*)d_in[5];
    float*       out    = (float*)d_out;

    float* M    = (float*)d_ws;            // 16*32*32 = 16384 floats
    float* bias = M + NC * CS * CS;        // 16*32   = 512 floats

    precompute_kernel<<<2, 256, 0, stream>>>(enc_w, enc_b, dec_w, dec_b, M, bias);
    ensemble_kernel<<<NBLOCKS, 256, 0, stream>>>(x, clus, M, bias, out);
}